// Round 1
// baseline (289.724 us; speedup 1.0000x reference)
//
#include <hip/hip_runtime.h>

// Problem constants (from reference)
#define B_     8
#define NCAM   5
#define J_     15
#define H_     128
#define W_     240
#define NBINS  128000           // 80*80*20
#define HW_    (H_ * W_)        // 30720 floats = 122880 bytes
#define NCHUNK 5                // bin chunks per (b,j)
#define BPB    (NBINS / NCHUNK) // 25600 bins per block
#define TPB    1024
#define ITEMS  (BPB / TPB)      // 25 bins per thread

// One block owns (b, j, chunk-of-25600-bins). For each camera:
//   stage heatmaps[b][n][j] (122.88 KB) into LDS, then each thread bilinearly
//   samples its 25 bins from LDS and accumulates in registers.
// Edge handling: corner validity (padding_mode='zeros') is folded into the
// per-column/per-row weights a0,a1,b0,b1 against a clamped 2x2 base window,
// so loads are always in-bounds and branchless.
__global__ __launch_bounds__(TPB) void project_kernel(
    const float* __restrict__ hm,     // [B, NCAM, J, H, W]
    const float* __restrict__ sgrid,  // [NCAM, NBINS, 2]
    float* __restrict__ out)          // [B, J, NBINS]
{
    extern __shared__ float s_img[];  // HW_ floats
    const int tid   = threadIdx.x;
    const int chunk = blockIdx.x % NCHUNK;
    const int bj    = blockIdx.x / NCHUNK;
    const int b     = bj / J_;
    const int j     = bj % J_;
    const int bin0  = chunk * BPB;

    float acc[ITEMS];
#pragma unroll
    for (int it = 0; it < ITEMS; ++it) acc[it] = 0.0f;

    for (int n = 0; n < NCAM; ++n) {
        __syncthreads();
        // ---- stage image (b, n, j) into LDS via float4 ----
        const float4* __restrict__ src =
            (const float4*)(hm + (((size_t)b * NCAM + n) * J_ + j) * HW_);
        float4* dst = (float4*)s_img;
        for (int i = tid; i < HW_ / 4; i += TPB) dst[i] = src[i];
        __syncthreads();

        const float* __restrict__ g = sgrid + ((size_t)n * NBINS + bin0) * 2;
#pragma unroll
        for (int it = 0; it < ITEMS; ++it) {
            const int bl = it * TPB + tid;       // local bin, coalesced per wave
            const float gx = g[2 * bl];
            const float gy = g[2 * bl + 1];
            // align_corners=True mapping
            const float ix = (gx + 1.0f) * (0.5f * (W_ - 1));
            const float iy = (gy + 1.0f) * (0.5f * (H_ - 1));
            const float x0f = floorf(ix);
            const float y0f = floorf(iy);
            const float wx1 = ix - x0f, wx0 = 1.0f - wx1;
            const float wy1 = iy - y0f, wy0 = 1.0f - wy1;
            const int x0 = (int)x0f;
            const int y0 = (int)y0f;
            // clamped 2x2 window base (always in-bounds)
            const int xc = min(max(x0, 0), W_ - 2);
            const int yc = min(max(y0, 0), H_ - 2);
            // validity-folded corner weights
            const float vx0 = (x0 >= 0  && x0 <= W_ - 1) ? wx0 : 0.0f;
            const float vx1 = (x0 >= -1 && x0 <= W_ - 2) ? wx1 : 0.0f;
            const float vy0 = (y0 >= 0  && y0 <= H_ - 1) ? wy0 : 0.0f;
            const float vy1 = (y0 >= -1 && y0 <= H_ - 2) ? wy1 : 0.0f;
            const bool xhi = (x0 == W_ - 1);  // corner x0 lands in column xc+1
            const bool xlo = (x0 == -1);      // corner x1 lands in column xc
            const bool yhi = (y0 == H_ - 1);
            const bool ylo = (y0 == -1);
            const float a0 = (xhi ? 0.0f : vx0) + (xlo ? vx1 : 0.0f);
            const float a1 = (xhi ? vx0 : 0.0f) + (xlo ? 0.0f : vx1);
            const float b0 = (yhi ? 0.0f : vy0) + (ylo ? vy1 : 0.0f);
            const float b1 = (yhi ? vy0 : 0.0f) + (ylo ? 0.0f : vy1);

            const float* r0 = s_img + (yc * W_ + xc);
            const float v00 = r0[0];
            const float v01 = r0[1];
            const float v10 = r0[W_];
            const float v11 = r0[W_ + 1];
            acc[it] += b0 * (a0 * v00 + a1 * v01) + b1 * (a0 * v10 + a1 * v11);
        }
    }

    // mean over cameras + clip, coalesced store
    float* __restrict__ o = out + (size_t)bj * NBINS + bin0;
#pragma unroll
    for (int it = 0; it < ITEMS; ++it) {
        const float v = acc[it] * 0.2f;
        o[it * TPB + tid] = fminf(fmaxf(v, 0.0f), 1.0f);
    }
}

extern "C" void kernel_launch(void* const* d_in, const int* in_sizes, int n_in,
                              void* d_out, int out_size, void* d_ws, size_t ws_size,
                              hipStream_t stream) {
    const float* hm = (const float*)d_in[0];   // heatmaps [8,5,15,128,240] f32
    const float* sg = (const float*)d_in[1];   // sample_grid [5,128000,2] f32
    float* out = (float*)d_out;                // [8,15,128000] f32

    const size_t smem = HW_ * sizeof(float);   // 122880 B > 64 KB static limit
    // opt-in to large dynamic LDS (gfx950: up to 160 KB/WG); idempotent, host-side
    (void)hipFuncSetAttribute((const void*)project_kernel,
                              hipFuncAttributeMaxDynamicSharedMemorySize,
                              (int)smem);

    const int grid = B_ * J_ * NCHUNK;  // 600 blocks
    project_kernel<<<grid, TPB, smem, stream>>>(hm, sg, out);
}